// Round 11
// baseline (358.373 us; speedup 1.0000x reference)
//
#include <hip/hip_runtime.h>
#include <hip/hip_bf16.h>
#include <stdint.h>

// Problem constants
constexpr int BATCH = 64;
constexpr int NTOK  = 197;
constexpr int CDIM  = 768;
constexpr int NH    = 12;
constexpr int HD    = 64;
constexpr int MROWS = BATCH * NTOK;        // 12608
constexpr int MPAD  = 12800;               // 100 * 128 (GEMM row tiles)
constexpr int NROWT = MPAD / 128;          // 100
constexpr int LEFT  = 137;                 // int(0.7 * 196)
constexpr int KPAD  = 224;                 // keys padded (7 * 32)
constexpr int BH    = BATCH * NH;          // 768
constexpr int SPAD  = 208;                 // score row stride

// Output layout (flat float32, concatenated in return order)
constexpr size_t OUT_OFF_OUT   = 0;                                   // [64,197,768]
constexpr size_t OUT_OFF_INDEX = (size_t)BATCH * NTOK * CDIM;         // [64,137,768]
constexpr size_t OUT_OFF_IDX   = OUT_OFF_INDEX + (size_t)BATCH * LEFT * CDIM; // [64,137]
constexpr size_t OUT_OFF_CLS   = OUT_OFF_IDX + (size_t)BATCH * LEFT;  // [64,196]

// Workspace layout (float units; bf16 regions counted as elems/2)
constexpr size_t WS_CLSPH = 0;                                        // (unused, kept for layout)
constexpr size_t WS_CLSF  = WS_CLSPH + (size_t)BH * (NTOK - 1);
constexpr size_t WS_IDXI  = WS_CLSF  + (size_t)BATCH * (NTOK - 1);
constexpr size_t WS_Q0    = WS_IDXI  + (size_t)BATCH * LEFT;          // qbW[BH] (reused region)
constexpr size_t WS_XB    = WS_Q0  + (size_t)BATCH * CDIM;            // [MPAD,768] bf16
constexpr size_t WS_WB    = WS_XB  + (size_t)MPAD * CDIM / 2;         // [2304,768] bf16
constexpr size_t WS_PB    = WS_WB  + (size_t)3 * CDIM * CDIM / 2;     // [768,768] bf16
constexpr size_t WS_QB    = WS_PB  + (size_t)CDIM * CDIM / 2;         // [BH,197,64] bf16
constexpr size_t WS_KB    = WS_QB  + (size_t)BH * NTOK * HD / 2;      // [BH,197,64] bf16
constexpr size_t WS_VTB   = WS_KB  + (size_t)BH * NTOK * HD / 2;      // dense v [MROWS,768] bf16 (region fits)
constexpr size_t WS_AOB   = WS_VTB + (size_t)BH * HD * KPAD / 2;      // [MPAD,768] bf16
constexpr size_t WS_U     = WS_AOB + (size_t)MPAD * CDIM / 2;         // [BH,768] fp32
constexpr size_t WS_S     = WS_U   + (size_t)BH * CDIM;               // [BH,208] fp32

typedef __attribute__((ext_vector_type(8))) short short8;
typedef __attribute__((ext_vector_type(4))) float floatx4;

__device__ __forceinline__ ushort f2bf(float x) {
    __hip_bfloat16 h = __float2bfloat16(x);
    return *(ushort*)&h;
}

// async global->LDS, 16B per lane; LDS dest must be wave-uniform base + lane*16
__device__ __forceinline__ void load_lds16(const ushort* g, ushort* l) {
    __builtin_amdgcn_global_load_lds(
        (const __attribute__((address_space(1))) uint32_t*)(uintptr_t)g,
        (__attribute__((address_space(3))) uint32_t*)(uint32_t)(uintptr_t)l,
        16, 0, 0);
}

// ---------------------------------------------------------------------------
// Fused prep: blocks [0, CASTB) cast x (padded to MPAD) / qkv_w / proj_w to
// bf16; blocks [CASTB, CASTB+BH) run the measured u_kernel (q0 slice + qb
// scalar + U row, exact fp32).
// ---------------------------------------------------------------------------
constexpr int X_N4  = MROWS * CDIM / 4;         // valid x float4s
constexpr int X_NP4 = MPAD * CDIM / 4;          // padded x float4s
constexpr int W_N4  = 3 * CDIM * CDIM / 4;
constexpr int P_N4  = CDIM * CDIM / 4;
constexpr int CAST_TOTAL = X_NP4 + W_N4 + P_N4; // multiple of 256
constexpr int CASTB = CAST_TOTAL / 256;         // 11904

__global__ __launch_bounds__(256) void prep_kernel(const float* __restrict__ x,
                                                   const float* __restrict__ qkv_w,
                                                   const float* __restrict__ proj_w,
                                                   const float* __restrict__ qkv_b,
                                                   ushort* __restrict__ xb,
                                                   ushort* __restrict__ wb,
                                                   ushort* __restrict__ pb,
                                                   float* __restrict__ U,
                                                   float* __restrict__ qbW) {
    const int bk = blockIdx.x;
    const int t  = threadIdx.x;

    if (bk < CASTB) {
        const int i = bk * 256 + t;
        const float* src; ushort* dst; int j, valid;
        if (i < X_NP4)             { src = x;      dst = xb; j = i;                valid = (j < X_N4); }
        else if (i < X_NP4 + W_N4) { src = qkv_w;  dst = wb; j = i - X_NP4;        valid = 1; }
        else                       { src = proj_w; dst = pb; j = i - X_NP4 - W_N4; valid = 1; }
        ushort4 h4 = make_ushort4(0, 0, 0, 0);
        if (valid) {
            float4 a = ((const float4*)src)[j];
            h4 = make_ushort4(f2bf(a.x), f2bf(a.y), f2bf(a.z), f2bf(a.w));
        }
        ((ushort4*)dst)[j] = h4;
        return;
    }

    // ---- u section: one block per (b,h) ----
    const int bh = bk - CASTB;
    const int b  = bh / NH;
    const int h  = bh - b * NH;
    const int wv   = t >> 6;
    const int lane = t & 63;

    __shared__ float x0s[CDIM];
    __shared__ float q0s[HD];

    if (t < 192) ((float4*)x0s)[t] = ((const float4*)(x + (size_t)b * NTOK * CDIM))[t];
    __syncthreads();

    // Phase A: 16 c's per wave (bitwise-identical reduction order to q0_kernel)
    for (int i = 0; i < 16; ++i) {
        const int cl = wv * 16 + i;            // 0..63
        const int c  = h * HD + cl;
        const float* wr = qkv_w + (size_t)c * CDIM;
        float s = 0.f;
#pragma unroll
        for (int k = 0; k < 3; ++k) {
            float4 xv  = *(const float4*)(x0s + lane * 4 + k * 256);
            float4 wv4 = *(const float4*)(wr  + lane * 4 + k * 256);
            s += xv.x * wv4.x + xv.y * wv4.y + xv.z * wv4.z + xv.w * wv4.w;
        }
#pragma unroll
        for (int off = 32; off >= 1; off >>= 1) s += __shfl_xor(s, off);
        if (lane == 0) q0s[cl] = s + qkv_b[c];
    }
    __syncthreads();

    // Phase B: qb scalar (wave 0)
    if (wv == 0) {
        float p = q0s[lane] * qkv_b[CDIM + h * HD + lane];
#pragma unroll
        for (int off = 32; off >= 1; off >>= 1) p += __shfl_xor(p, off);
        if (lane == 0) qbW[bh] = p;
    }

    // Phase C: U row
    const float* wk = qkv_w + (size_t)(CDIM + h * HD) * CDIM;
    float a0 = 0.f, a1 = 0.f, a2 = 0.f;
    for (int d = 0; d < HD; d++) {
        const float qd = q0s[d];
        const float* row = wk + (size_t)d * CDIM;
        a0 = fmaf(qd, row[t],       a0);
        a1 = fmaf(qd, row[t + 256], a1);
        a2 = fmaf(qd, row[t + 512], a2);
    }
    float* ub = U + (size_t)bh * CDIM;
    ub[t] = a0; ub[t + 256] = a1; ub[t + 512] = a2;
}

// ---------------------------------------------------------------------------
// Fused score + cls softmax + head-average + exact top-137: ONE block per
// batch (512 threads).  Scores for all 197 tokens x 12 heads computed into
// LDS (same per-(j,h) dot + shfl order as the previous score_kernel), then
// the R10 topk section runs in-block (redm/reds written by waves 0-3 only —
// numerics bitwise-identical; waves 4-7 pass through the barriers).
// Removes the topk dispatch and the S global roundtrip.
// ---------------------------------------------------------------------------
__global__ __launch_bounds__(512) void score_topk_kernel(const float* __restrict__ x,
                                                         const float* __restrict__ U,
                                                         const float* __restrict__ qbW,
                                                         int* __restrict__ idxI,
                                                         float* __restrict__ idxOut,
                                                         float* __restrict__ outCls) {
    const int b    = blockIdx.x;
    const int t    = threadIdx.x;
    const int wv   = t >> 6;
    const int lane = t & 63;

    __shared__ float Us[NH][CDIM];          // 36 KiB
    __shared__ float Ssh[NH][200];          // 9.6 KiB
    __shared__ float qbv[NH];
    __shared__ float redm[4], reds[4];
    __shared__ float vsh[NTOK - 1];

    for (int i = t; i < NH * (CDIM / 4); i += 512)
        ((float4*)Us)[i] = ((const float4*)(U + (size_t)b * NH * CDIM))[i];
    if (t < NH) qbv[t] = qbW[b * NH + t];
    __syncthreads();

    // ---- score: wave wv handles j = wv, wv+8, ... ----
    for (int j = wv; j < NTOK; j += 8) {
        const float* xr = x + ((size_t)b * NTOK + j) * CDIM;
        float4 xv[3];
#pragma unroll
        for (int i = 0; i < 3; i++) xv[i] = *(const float4*)(xr + lane * 4 + i * 256);
        for (int h = 0; h < NH; h++) {
            const float* ur = Us[h];
            float s = 0.f;
#pragma unroll
            for (int i = 0; i < 3; i++) {
                float4 uv = *(const float4*)(ur + lane * 4 + i * 256);
                s += xv[i].x * uv.x + xv[i].y * uv.y + xv[i].z * uv.z + xv[i].w * uv.w;
            }
#pragma unroll
            for (int off = 32; off >= 1; off >>= 1) s += __shfl_xor(s, off);
            if (lane == 0) Ssh[h][j] = s;
        }
    }
    __syncthreads();

    // ---- topk (identical numeric path to R10; waves 4-7 don't write) ----
    float macc = 0.f;
    for (int h = 0; h < NH; ++h) {
        const float qb = qbv[h];
        const float sv = (t < NTOK) ? (Ssh[h][t] + qb) * 0.125f : -INFINITY;
        float mloc = sv;
#pragma unroll
        for (int off = 32; off >= 1; off >>= 1) mloc = fmaxf(mloc, __shfl_xor(mloc, off));
        if (lane == 0 && wv < 4) redm[wv] = mloc;
        __syncthreads();
        const float mx = fmaxf(fmaxf(redm[0], redm[1]), fmaxf(redm[2], redm[3]));
        const float p = (t < NTOK) ? expf(sv - mx) : 0.f;
        float ls = p;
#pragma unroll
        for (int off = 32; off >= 1; off >>= 1) ls += __shfl_xor(ls, off);
        if (lane == 0 && wv < 4) reds[wv] = ls;
        __syncthreads();
        const float denom = (reds[0] + reds[1]) + (reds[2] + reds[3]);
        macc += p / denom;
        __syncthreads();                  // protect redm/reds for next h
    }

    if (t >= 1 && t < NTOK) {
        const float val = macc * (1.f / 12.f);
        vsh[t - 1] = val;
        outCls[(size_t)b * (NTOK - 1) + (t - 1)] = val;
    }
    __syncthreads();

    if (t < NTOK - 1) {
        const float vi = vsh[t];
        int rank = 0;
        for (int j = 0; j < NTOK - 1; j++) {
            const float vj = vsh[j];
            rank += (vj > vi) || (vj == vi && j < t);
        }
        if (rank < LEFT) {
            idxI[b * LEFT + rank]   = t;
            idxOut[b * LEFT + rank] = (float)t;
        }
    }
}

// ---------------------------------------------------------------------------
// 128x128 / BK=32 / 4-wave bf16 MFMA GEMM — R4/R6/R8-measured m97 geometry.
// BOTH epilogues are LDS-RESTAGED for full-line coalesced stores (R10: the
// MODE-1 restage cut QKV WRITE_SIZE 133->57MB and dur 100->72us; MODE 0 had
// 64B-segment fp32 stores -> same fix, [64][128] float tile = 32KB exactly).
// MODE 0: fp32 row-major O0f[Mvalid, N] via LDS restage (512B row runs).
// MODE 1: q -> O0q[bh][tok][64], k -> O1k[bh][tok][64], v -> dense
//         O2vd[m][768]; via LDS restage (128B/256B runs).
// ---------------------------------------------------------------------------
template <int MODE, int NCOLT>
__global__ __launch_bounds__(256, 4) void mfma_gemm128(
    const ushort* __restrict__ A, const ushort* __restrict__ W,
    const float* __restrict__ bias,
    float* __restrict__ O0f, ushort* __restrict__ O0q,
    ushort* __restrict__ O1k, ushort* __restrict__ O2vd,
    int Mvalid, int N) {
    constexpr int K   = CDIM;               // 768
    constexpr int BK  = 32;
    constexpr int NTK = K / BK;             // 24
    constexpr int nwg = NROWT * NCOLT;
    __shared__ ushort smem[16384];          // 32 KiB: sA(16K) + sB(16K)
    ushort* sA = smem;
    ushort* sB = smem + 8192;

    const int t    = threadIdx.x;
    const int lane = t & 63;
    const int w    = t >> 6;
    const int wm   = (w >> 1) * 64;         // M-half of tile
    const int wn   = (w & 1) * 64;          // N-half of tile
    const int fr   = lane & 15;
    const int fq   = lane >> 4;             // 0..3
    const int f3   = lane & 3;              // == fr & 3

    // bijective XCD-aware swizzle (m204): contiguous wgid chunk per XCD
    int row, col;
    {
        constexpr int q = nwg >> 3, r = nwg & 7;
        const int xcd = blockIdx.x & 7, lin = blockIdx.x >> 3;
        const int wg = (xcd < r ? xcd * (q + 1) : r * (q + 1) + (xcd - r) * q) + lin;
        row = wg / NCOLT; col = wg - row * NCOLT;
    }
    const int rowBase = row * 128;
    const int colBase = col * 128;

    // stage one 128x32 tile (8 KB): linear LDS dest, inverse-swizzled source
    auto stage = [&](const ushort* __restrict__ G, ushort* dst, int grow0, int kt) {
#pragma unroll
        for (int i = 0; i < 2; ++i) {
            const int l  = i * 256 + t;
            const int rl = l >> 2;                       // row (4 thr/row)
            const int sl = (l & 3) ^ (rl & 3);           // swizzled 16B slot
            load_lds16(G + (size_t)(grow0 + rl) * K + kt * BK + sl * 8,
                       dst + l * 8);
        }
    };

    floatx4 acc[4][4];
#pragma unroll
    for (int i = 0; i < 4; ++i)
#pragma unroll
        for (int j = 0; j < 4; ++j)
#pragma unroll
            for (int r2 = 0; r2 < 4; ++r2) acc[i][j][r2] = 0.f;

    // read-side swizzled slot offset (ushort units): logical slot fq
    const int s0 = (fq ^ f3) * 8;

    // prologue: tile 0 -> buffer 0
    stage(A, sA, rowBase, 0);
    stage(W, sB, colBase, 0);

    for (int kt = 0; kt < NTK; ++kt) {
        __syncthreads();                     // drains vm+lgkm: buf[cur] ready,
                                             // buf[cur^1] reads complete
        const int cb = (kt & 1) << 12;       // current buffer (ushort offset)
        if (kt + 1 < NTK) {                  // prefetch next tile
            stage(A, sA + (cb ^ 4096), rowBase, kt + 1);
            stage(W, sB + (cb ^ 4096), colBase, kt + 1);
        }

        const ushort* pa = sA + cb + (wm + fr) * BK;
        const ushort* pb = sB + cb + (wn + fr) * BK;
        short8 af[4], bf[4];
#pragma unroll
        for (int i = 0; i < 4; ++i) {
            af[i] = *(const short8*)(pa + i * 512 + s0);
            bf[i] = *(const short8*)(pb + i * 512 + s0);
        }
#pragma unroll
        for (int i = 0; i < 4; ++i)
#pragma unroll
            for (int j = 0; j < 4; ++j)
                acc[i][j] = __builtin_amdgcn_mfma_f32_16x16x32_bf16(
                    af[i], bf[j], acc[i][j], 0, 0, 0);
    }

    // epilogue: C/D layout col(n)=lane&15, row(m)=(lane>>4)*4+reg
    const int hpw = wm >> 6;                 // this wave's row-half
    if (MODE == 0) {
        // LDS-restaged fp32 stores: [64][128] float tile = 32 KiB exactly
        float (*Tf)[128] = (float (*)[128])smem;
#pragma unroll
        for (int hp = 0; hp < 2; ++hp) {
            __syncthreads();                 // prior smem uses complete
            if (hpw == hp) {
#pragma unroll
                for (int j = 0; j < 4; ++j) {
                    const int nl = wn + j * 16 + fr;
                    const float bq = bias[colBase + nl];
#pragma unroll
                    for (int i = 0; i < 4; ++i)
#pragma unroll
                        for (int r2 = 0; r2 < 4; ++r2)
                            Tf[i * 16 + fq * 4 + r2][nl] = acc[i][j][r2] + bq;
                }
            }
            __syncthreads();
            const int rowH = rowBase + hp * 64;
#pragma unroll
            for (int it = 0; it < 8; ++it) {
                const int lr = it * 8 + (t >> 5);       // 0..63
                const int c4 = (t & 31) * 4;            // float col
                const int mm = rowH + lr;
                if (mm < Mvalid)
                    *(float4*)(O0f + (size_t)mm * N + colBase + c4) =
                        *(const float4*)&Tf[lr][c4];
            }
        }
    } else {
        // LDS-restaged coalesced bf16 stores: two 64-row passes through smem
        const int which = colBase / CDIM;       // 0=q 1=k 2=v, block-uniform
        const int nc0   = colBase - which * CDIM;
        const int hbase = nc0 >> 6;
        ushort (*T)[136] = (ushort (*)[136])smem;   // 64 x 136 = 17 KiB
#pragma unroll
        for (int hp = 0; hp < 2; ++hp) {
            __syncthreads();                    // prior reads/writes of smem done
            if (hpw == hp) {
#pragma unroll
                for (int j = 0; j < 4; ++j) {
                    const int nl = wn + j * 16 + fr;
                    const float bq = bias[colBase + nl];
#pragma unroll
                    for (int i = 0; i < 4; ++i)
#pragma unroll
                        for (int r2 = 0; r2 < 4; ++r2)
                            T[i * 16 + fq * 4 + r2][nl] = f2bf(acc[i][j][r2] + bq);
                }
            }
            __syncthreads();
            const int rowH = rowBase + hp * 64;
            if (which < 2) {
                ushort* O = (which == 0) ? O0q : O1k;
#pragma unroll
                for (int it = 0; it < 4; ++it) {
                    const int run = it * 32 + (t >> 3);   // 64 rows x 2 heads
                    const int lr  = run >> 1;
                    const int hh  = run & 1;
                    const int d0  = (t & 7) * 8;
                    const int mm  = rowH + lr;
                    if (mm < Mvalid) {
                        const int b   = mm / NTOK;
                        const int tok = mm - b * NTOK;
                        *(short8*)(O + (((size_t)(b * NH + hbase + hh) * NTOK + tok) * HD + d0)) =
                            *(const short8*)&T[lr][hh * 64 + d0];
                    }
                }
            } else {
#pragma unroll
                for (int it = 0; it < 4; ++it) {
                    const int lr = it * 16 + (t >> 4);
                    const int c8 = (t & 15) * 8;
                    const int mm = rowH + lr;
                    if (mm < Mvalid)
                        *(short8*)(O2vd + ((size_t)mm * CDIM + nc0 + c8)) =
                            *(const short8*)&T[lr][c8];
                }
            }
        }
    }
}

// ---------------------------------------------------------------------------
// MFMA flash attention, one block per (b,h): 4 waves share an LDS-transposed
// V tile staged from the GEMM's dense v output via short8 loads.  Wave wv
// owns q-tile groups {0-3},{4-6},{7-9},{10-12}.  Tail blocks (>= BH) run the
// index-broadcast fill (grid-stride; overlaps the latency-bound attention).
// ---------------------------------------------------------------------------
constexpr int FILLB    = 256;                       // fill tail blocks
constexpr int FILL_TOT = BATCH * LEFT * (CDIM / 4); // float4s

__global__ __launch_bounds__(256) void attn_mfma_kernel(const ushort* __restrict__ Qb,
                                                        const ushort* __restrict__ Kb,
                                                        const ushort* __restrict__ Vd,
                                                        ushort* __restrict__ AOb,
                                                        const int* __restrict__ idxI,
                                                        float* __restrict__ fillDst) {
    if (blockIdx.x >= BH) {                 // block-uniform; no barriers touched
        const int fb = blockIdx.x - BH;
        for (int i = fb * 256 + (int)threadIdx.x; i < FILL_TOT; i += FILLB * 256) {
            const float v = (float)idxI[i / (CDIM / 4)];
            ((float4*)fillDst)[i] = make_float4(v, v, v, v);
        }
        return;
    }

    const int bh = blockIdx.x;          // 0..767
    const int b  = bh / NH;
    const int h  = bh - b * NH;
    const int t  = threadIdx.x;
    const int wv   = t >> 6;
    const int lane = t & 63;
    const int qc   = lane & 15;
    const int quad = lane >> 4;

    constexpr int VSTR = KPAD + 8;      // 232 ushorts (464B rows, 16B-aligned)
    __shared__ ushort Vt[HD][VSTR];     // 29.7 KiB
    __shared__ ushort Pl[4][4][16][32]; // 16 KiB (per wave x per tile)
    __shared__ float  alf[4][4][16], lf[4][4][16];

    // stage V transposed: each thread loads 8 consecutive d's of one tok (16B)
    {
        for (int idx = t; idx < NTOK * 8; idx += 256) {
            const int tok = idx >> 3;
            const int d0  = (idx & 7) * 8;
            const short8 v = *(const short8*)(
                Vd + ((size_t)(b * NTOK + tok)) * CDIM + h * HD + d0);
#pragma unroll
            for (int jj = 0; jj < 8; ++jj) Vt[d0 + jj][tok] = (ushort)v[jj];
        }
        for (int idx = t; idx < (KPAD - NTOK) * HD; idx += 256) {
            const int tok = NTOK + (idx >> 6);
            const int d   = idx & 63;
            Vt[d][tok] = 0;
        }
    }

    const ushort* Qh = Qb + (size_t)bh * NTOK * HD;
    const ushort* Kh = Kb + (size_t)bh * NTOK * HD;

    const int tile0 = (wv == 0) ? 0 : 4 + (wv - 1) * 3;   // 0,4,7,10
    const int ntv   = (wv == 0) ? 4 : 3;

    short8 qf[4][2];
#pragma unroll
    for (int ti = 0; ti < 4; ++ti) {
        if (ti < ntv) {
            const int qrow = min((tile0 + ti) * 16 + qc, NTOK - 1);
            qf[ti][0] = *(const short8*)(Qh + (size_t)qrow * HD + quad * 8);
            qf[ti][1] = *(const short8*)(Qh + (size_t)qrow * HD + 32 + quad * 8);
        }
    }

    floatx4 o[4][4];
#pragma unroll
    for (int ti = 0; ti < 4; ++ti)
#pragma unroll
        for (int s = 0; s < 4; ++s)
#pragma unroll
            for (int r = 0; r < 4; ++r) o[ti][s][r] = 0.f;
    float m[4], l[4];
#pragma unroll
    for (int ti = 0; ti < 4; ++ti) { m[ti] = -INFINITY; l[ti] = 0.f; }

    __syncthreads();                    // Vt ready

    for (int c0 = 0; c0 < NTOK; c0 += 32) {
        const int kr0 = min(c0 + qc, NTOK - 1);
        const int kr1 = min(c0 + 16 + qc, NTOK - 1);
        const short8 kf00 = *(const short8*)(Kh + (size_t)kr0 * HD + quad * 8);
        const short8 kf01 = *(const short8*)(Kh + (size_t)kr0 * HD + 32 + quad * 8);
        const short8 kf10 = *(const short8*)(Kh + (size_t)kr1 * HD + quad * 8);
        const short8 kf11 = *(const short8*)(Kh + (size_t)kr1 * HD + 32 + quad * 8);

#pragma unroll
        for (int ti = 0; ti < 4; ++ti) {
            if (ti >= ntv) continue;    // wave-uniform guard
            floatx4 s0 = {0.f, 0.f, 0.f, 0.f}, s1 = {0.f, 0.f, 0.f, 0.f};
            s0 = __builtin_amdgcn_mfma_f32_16x16x32_bf16(kf00, qf[ti][0], s0, 0, 0, 0);
            s0 = __builtin_amdgcn_mfma_f32_16x16x32_bf16(kf01, qf[ti][1], s0, 0, 0, 0);
            s1 = __builtin_amdgcn_mfma_f32_16x16x32_bf16(kf10, qf[ti][0], s1, 0, 0, 0);
            s1 = __builtin_amdgcn_mfma_f32_16x16x32_bf16(kf11, qf[ti][1], s1, 0, 0, 0);

            float sv[8];
            float mloc = -INFINITY;
#pragma unroll
            for (int r = 0; r < 4; ++r) {
                const int key0 = c0 + quad * 4 + r;
                const int key1 = key0 + 16;
                sv[r]     = (key0 < NTOK) ? s0[r] * 0.125f : -1e30f;
                sv[4 + r] = (key1 < NTOK) ? s1[r] * 0.125f : -1e30f;
                mloc = fmaxf(mloc, fmaxf(sv[r], sv[4 + r]));
            }
            mloc = fmaxf(mloc, __shfl_xor(mloc, 16));
            mloc = fmaxf(mloc, __shfl_xor(mloc, 32));
            const float mnew  = fmaxf(m[ti], mloc);
            const float alpha = __expf(m[ti] - mnew);
            float p[8], ps = 0.f;
#pragma unroll
            for (int i = 0; i < 8; ++i) { p[i] = __expf(sv[i] - mnew); ps += p[i]; }
            ps += __shfl_xor(ps, 16);
            ps += __shfl_xor(ps, 32);
            l[ti] = l[ti] * alpha + ps;
            m[ti] = mnew;

#pragma unroll
            for (int r = 0; r < 4; ++r) {
                Pl[wv][ti][qc][quad * 4 + r]      = f2bf(p[r]);
                Pl[wv][ti][qc][16 + quad * 4 + r] = f2bf(p[4 + r]);
            }
            if (quad == 0) alf[wv][ti][qc] = alpha;
        }
        __syncthreads();

        short8 pf[4];
#pragma unroll
        for (int ti = 0; ti < 4; ++ti) {
            if (ti >= ntv) continue;
            pf[ti] = *(const short8*)&Pl[wv][ti][qc][quad * 8];
            float ar[4];
#pragma unroll
            for (int r = 0; r < 4; ++r) ar[r] = alf[wv][ti][quad * 4 + r];
#pragma unroll
            for (int s = 0; s < 4; ++s)
#pragma unroll
                for (int r = 0; r < 4; ++r) o[ti][s][r] *= ar[r];
        }

#pragma unroll
        for (int s = 0; s < 4; ++s) {
            const short8 vf = *(const short8*)&Vt[s * 16 + qc][c0 + quad * 8];
#pragma unroll
            for (int ti = 0; ti < 4; ++ti)
                if (ti < ntv)
                    o[ti][s] = __builtin_amdgcn_mfma_f32_16x16x32_bf16(
                        pf[ti], vf, o[ti][s], 0, 0, 0);
        }
        __syncthreads();                // Pl reused next step
    }

#pragma unroll
    for (int ti = 0; ti < 4; ++ti)
        if (ti < ntv && quad == 0) lf[wv][ti][qc] = l[ti];
    __syncthreads();

#pragma unroll
    for (int ti = 0; ti < 4; ++ti) {
        if (ti >= ntv) continue;
        const int qt = tile0 + ti;
#pragma unroll
        for (int r = 0; r < 4; ++r) {
            const int tok = qt * 16 + quad * 4 + r;
            if (tok >= NTOK) continue;
            const float inv = 1.f / lf[wv][ti][quad * 4 + r];
            ushort* dst = AOb + ((size_t)(b * NTOK + tok)) * CDIM + h * HD;
#pragma unroll
            for (int s = 0; s < 4; ++s) dst[s * 16 + qc] = f2bf(o[ti][s][r] * inv);
        }
    }
}

extern "C" void kernel_launch(void* const* d_in, const int* in_sizes, int n_in,
                              void* d_out, int out_size, void* d_ws, size_t ws_size,
                              hipStream_t stream) {
    const float* x      = (const float*)d_in[0];
    const float* qkv_w  = (const float*)d_in[1];  // [2304,768]
    const float* qkv_b  = (const float*)d_in[2];  // [2304]
    const float* proj_w = (const float*)d_in[3];  // [768,768]
    const float* proj_b = (const float*)d_in[4];  // [768]
    float* out = (float*)d_out;

    float*  ws    = (float*)d_ws;
    int*    idxi  = (int*)(ws + WS_IDXI);
    float*  qbW   = ws + WS_Q0;
    ushort* xb    = (ushort*)(ws + WS_XB);
    ushort* wb    = (ushort*)(ws + WS_WB);
    ushort* pb    = (ushort*)(ws + WS_PB);
    ushort* qb    = (ushort*)(ws + WS_QB);
    ushort* kb    = (ushort*)(ws + WS_KB);
    ushort* vd    = (ushort*)(ws + WS_VTB);  // dense v [MROWS][768]
    ushort* aob   = (ushort*)(ws + WS_AOB);
    float*  U     = ws + WS_U;

    // 1) fused prep: bf16 casts + exact fp32 q0/qb/U side path
    prep_kernel<<<CASTB + BH, 256, 0, stream>>>(x, qkv_w, proj_w, qkv_b,
                                                xb, wb, pb, U, qbW);

    // 2) fused cls scores + softmax + head-average + exact top-137
    score_topk_kernel<<<BATCH, 512, 0, stream>>>(x, U, qbW, idxi,
                                                 out + OUT_OFF_IDX,
                                                 out + OUT_OFF_CLS);

    // 3) QKV projection (128²/BK32 MFMA) + LDS-restaged coalesced q/k/v stores
    mfma_gemm128<1, 18><<<NROWT * 18, 256, 0, stream>>>(
        xb, wb, qkv_b, nullptr, qb, kb, vd, MROWS, 3 * CDIM);

    // 4) MFMA flash attention (block per bh; in-LDS V transpose) -> bf16 out;
    //    fill_index piggybacked on 256 tail blocks (overlaps attn latency)
    attn_mfma_kernel<<<BH + FILLB, 256, 0, stream>>>(qb, kb, vd, aob,
                                                     idxi, out + OUT_OFF_INDEX);

    // 5) Output projection (128²/BK32 MFMA, LDS-restaged fp32 stores)
    mfma_gemm128<0, 6><<<NROWT * 6, 256, 0, stream>>>(
        aob, pb, proj_b, out + OUT_OFF_OUT, nullptr, nullptr, nullptr,
        MROWS, CDIM);
}

// Round 12
// 300.767 us; speedup vs baseline: 1.1915x; 1.1915x over previous
//
#include <hip/hip_runtime.h>
#include <hip/hip_bf16.h>
#include <stdint.h>

// Problem constants
constexpr int BATCH = 64;
constexpr int NTOK  = 197;
constexpr int CDIM  = 768;
constexpr int NH    = 12;
constexpr int HD    = 64;
constexpr int MROWS = BATCH * NTOK;        // 12608
constexpr int MPAD  = 12800;               // 100 * 128 (GEMM row tiles)
constexpr int NROWT = MPAD / 128;          // 100
constexpr int LEFT  = 137;                 // int(0.7 * 196)
constexpr int KPAD  = 224;                 // keys padded (7 * 32)
constexpr int BH    = BATCH * NH;          // 768
constexpr int SPAD  = 208;                 // score row stride

// Output layout (flat float32, concatenated in return order)
constexpr size_t OUT_OFF_OUT   = 0;                                   // [64,197,768]
constexpr size_t OUT_OFF_INDEX = (size_t)BATCH * NTOK * CDIM;         // [64,137,768]
constexpr size_t OUT_OFF_IDX   = OUT_OFF_INDEX + (size_t)BATCH * LEFT * CDIM; // [64,137]
constexpr size_t OUT_OFF_CLS   = OUT_OFF_IDX + (size_t)BATCH * LEFT;  // [64,196]

// Workspace layout (float units; bf16 regions counted as elems/2)
constexpr size_t WS_CLSPH = 0;                                        // (unused, kept for layout)
constexpr size_t WS_CLSF  = WS_CLSPH + (size_t)BH * (NTOK - 1);
constexpr size_t WS_IDXI  = WS_CLSF  + (size_t)BATCH * (NTOK - 1);
constexpr size_t WS_Q0    = WS_IDXI  + (size_t)BATCH * LEFT;          // qbW[BH] (reused region)
constexpr size_t WS_XB    = WS_Q0  + (size_t)BATCH * CDIM;            // [MPAD,768] bf16
constexpr size_t WS_WB    = WS_XB  + (size_t)MPAD * CDIM / 2;         // [2304,768] bf16
constexpr size_t WS_PB    = WS_WB  + (size_t)3 * CDIM * CDIM / 2;     // [768,768] bf16
constexpr size_t WS_QB    = WS_PB  + (size_t)CDIM * CDIM / 2;         // [BH,197,64] bf16
constexpr size_t WS_KB    = WS_QB  + (size_t)BH * NTOK * HD / 2;      // [BH,197,64] bf16
constexpr size_t WS_VTB   = WS_KB  + (size_t)BH * NTOK * HD / 2;      // dense v [MROWS,768] bf16 (region fits)
constexpr size_t WS_AOB   = WS_VTB + (size_t)BH * HD * KPAD / 2;      // [MPAD,768] bf16
constexpr size_t WS_U     = WS_AOB + (size_t)MPAD * CDIM / 2;         // [BH,768] fp32
constexpr size_t WS_S     = WS_U   + (size_t)BH * CDIM;               // [BH,208] fp32

typedef __attribute__((ext_vector_type(8))) short short8;
typedef __attribute__((ext_vector_type(4))) float floatx4;

__device__ __forceinline__ ushort f2bf(float x) {
    __hip_bfloat16 h = __float2bfloat16(x);
    return *(ushort*)&h;
}

// async global->LDS, 16B per lane; LDS dest must be wave-uniform base + lane*16
__device__ __forceinline__ void load_lds16(const ushort* g, ushort* l) {
    __builtin_amdgcn_global_load_lds(
        (const __attribute__((address_space(1))) uint32_t*)(uintptr_t)g,
        (__attribute__((address_space(3))) uint32_t*)(uint32_t)(uintptr_t)l,
        16, 0, 0);
}

// ---------------------------------------------------------------------------
// Fused prep: blocks [0, CASTB) cast x (padded to MPAD) / qkv_w / proj_w to
// bf16; blocks [CASTB, CASTB+BH) run the measured u_kernel (q0 slice + qb
// scalar + U row, exact fp32).
// ---------------------------------------------------------------------------
constexpr int X_N4  = MROWS * CDIM / 4;         // valid x float4s
constexpr int X_NP4 = MPAD * CDIM / 4;          // padded x float4s
constexpr int W_N4  = 3 * CDIM * CDIM / 4;
constexpr int P_N4  = CDIM * CDIM / 4;
constexpr int CAST_TOTAL = X_NP4 + W_N4 + P_N4; // multiple of 256
constexpr int CASTB = CAST_TOTAL / 256;         // 11904

__global__ __launch_bounds__(256) void prep_kernel(const float* __restrict__ x,
                                                   const float* __restrict__ qkv_w,
                                                   const float* __restrict__ proj_w,
                                                   const float* __restrict__ qkv_b,
                                                   ushort* __restrict__ xb,
                                                   ushort* __restrict__ wb,
                                                   ushort* __restrict__ pb,
                                                   float* __restrict__ U,
                                                   float* __restrict__ qbW) {
    const int bk = blockIdx.x;
    const int t  = threadIdx.x;

    if (bk < CASTB) {
        const int i = bk * 256 + t;
        const float* src; ushort* dst; int j, valid;
        if (i < X_NP4)             { src = x;      dst = xb; j = i;                valid = (j < X_N4); }
        else if (i < X_NP4 + W_N4) { src = qkv_w;  dst = wb; j = i - X_NP4;        valid = 1; }
        else                       { src = proj_w; dst = pb; j = i - X_NP4 - W_N4; valid = 1; }
        ushort4 h4 = make_ushort4(0, 0, 0, 0);
        if (valid) {
            float4 a = ((const float4*)src)[j];
            h4 = make_ushort4(f2bf(a.x), f2bf(a.y), f2bf(a.z), f2bf(a.w));
        }
        ((ushort4*)dst)[j] = h4;
        return;
    }

    // ---- u section: one block per (b,h) ----
    const int bh = bk - CASTB;
    const int b  = bh / NH;
    const int h  = bh - b * NH;
    const int wv   = t >> 6;
    const int lane = t & 63;

    __shared__ float x0s[CDIM];
    __shared__ float q0s[HD];

    if (t < 192) ((float4*)x0s)[t] = ((const float4*)(x + (size_t)b * NTOK * CDIM))[t];
    __syncthreads();

    // Phase A: 16 c's per wave (bitwise-identical reduction order to q0_kernel)
    for (int i = 0; i < 16; ++i) {
        const int cl = wv * 16 + i;            // 0..63
        const int c  = h * HD + cl;
        const float* wr = qkv_w + (size_t)c * CDIM;
        float s = 0.f;
#pragma unroll
        for (int k = 0; k < 3; ++k) {
            float4 xv  = *(const float4*)(x0s + lane * 4 + k * 256);
            float4 wv4 = *(const float4*)(wr  + lane * 4 + k * 256);
            s += xv.x * wv4.x + xv.y * wv4.y + xv.z * wv4.z + xv.w * wv4.w;
        }
#pragma unroll
        for (int off = 32; off >= 1; off >>= 1) s += __shfl_xor(s, off);
        if (lane == 0) q0s[cl] = s + qkv_b[c];
    }
    __syncthreads();

    // Phase B: qb scalar (wave 0)
    if (wv == 0) {
        float p = q0s[lane] * qkv_b[CDIM + h * HD + lane];
#pragma unroll
        for (int off = 32; off >= 1; off >>= 1) p += __shfl_xor(p, off);
        if (lane == 0) qbW[bh] = p;
    }

    // Phase C: U row
    const float* wk = qkv_w + (size_t)(CDIM + h * HD) * CDIM;
    float a0 = 0.f, a1 = 0.f, a2 = 0.f;
    for (int d = 0; d < HD; d++) {
        const float qd = q0s[d];
        const float* row = wk + (size_t)d * CDIM;
        a0 = fmaf(qd, row[t],       a0);
        a1 = fmaf(qd, row[t + 256], a1);
        a2 = fmaf(qd, row[t + 512], a2);
    }
    float* ub = U + (size_t)bh * CDIM;
    ub[t] = a0; ub[t + 256] = a1; ub[t + 512] = a2;
}

// ---------------------------------------------------------------------------
// S[bh, j] = u[bh,:] . x[b,j,:]   — 8 waves per block, U[12][768] staged in
// LDS once per block.  (R11's 64-block fusion of this with topk collapsed
// parallelism 1600->64 blocks and cost 73us — kept SEPARATE.)
// ---------------------------------------------------------------------------
__global__ __launch_bounds__(512) void score_kernel(const float* __restrict__ x,
                                                    const float* __restrict__ U,
                                                    float* __restrict__ S) {
    const int b    = blockIdx.y;
    const int wv   = threadIdx.x >> 6;
    const int lane = threadIdx.x & 63;

    __shared__ float Us[NH][CDIM];          // 36 KiB
    for (int i = threadIdx.x; i < NH * (CDIM / 4); i += 512)
        ((float4*)Us)[i] = ((const float4*)(U + (size_t)b * NH * CDIM))[i];
    __syncthreads();

    const int j = blockIdx.x * 8 + wv;
    if (j >= NTOK) return;

    const float* xr = x + ((size_t)b * NTOK + j) * CDIM;
    float4 xv[3];
#pragma unroll
    for (int i = 0; i < 3; i++) xv[i] = *(const float4*)(xr + lane * 4 + i * 256);

    for (int h = 0; h < NH; h++) {
        const float* ur = Us[h];
        float s = 0.f;
#pragma unroll
        for (int i = 0; i < 3; i++) {
            float4 uv = *(const float4*)(ur + lane * 4 + i * 256);
            s += xv[i].x * uv.x + xv[i].y * uv.y + xv[i].z * uv.z + xv[i].w * uv.w;
        }
#pragma unroll
        for (int off = 32; off >= 1; off >>= 1) s += __shfl_xor(s, off);
        if (lane == 0) S[(size_t)(b * NH + h) * SPAD + j] = s;
    }
}

// ---------------------------------------------------------------------------
// 128x128 / BK=32 / 4-wave bf16 MFMA GEMM — R4/R6/R8-measured m97 geometry.
// BOTH epilogues are LDS-RESTAGED for full-line coalesced stores (R10: the
// MODE-1 restage cut QKV WRITE_SIZE 133->57MB and dur 100->72us; R11's
// MODE-0 restage fixes the 64B-segment fp32 stores the same way).
// MODE 0: fp32 row-major O0f[Mvalid, N] via LDS restage (512B row runs).
// MODE 1: q -> O0q[bh][tok][64], k -> O1k[bh][tok][64], v -> dense
//         O2vd[m][768]; via LDS restage (128B/256B runs).
// ---------------------------------------------------------------------------
template <int MODE, int NCOLT>
__global__ __launch_bounds__(256, 4) void mfma_gemm128(
    const ushort* __restrict__ A, const ushort* __restrict__ W,
    const float* __restrict__ bias,
    float* __restrict__ O0f, ushort* __restrict__ O0q,
    ushort* __restrict__ O1k, ushort* __restrict__ O2vd,
    int Mvalid, int N) {
    constexpr int K   = CDIM;               // 768
    constexpr int BK  = 32;
    constexpr int NTK = K / BK;             // 24
    constexpr int nwg = NROWT * NCOLT;
    __shared__ ushort smem[16384];          // 32 KiB: sA(16K) + sB(16K)
    ushort* sA = smem;
    ushort* sB = smem + 8192;

    const int t    = threadIdx.x;
    const int lane = t & 63;
    const int w    = t >> 6;
    const int wm   = (w >> 1) * 64;         // M-half of tile
    const int wn   = (w & 1) * 64;          // N-half of tile
    const int fr   = lane & 15;
    const int fq   = lane >> 4;             // 0..3
    const int f3   = lane & 3;              // == fr & 3

    // bijective XCD-aware swizzle (m204): contiguous wgid chunk per XCD
    int row, col;
    {
        constexpr int q = nwg >> 3, r = nwg & 7;
        const int xcd = blockIdx.x & 7, lin = blockIdx.x >> 3;
        const int wg = (xcd < r ? xcd * (q + 1) : r * (q + 1) + (xcd - r) * q) + lin;
        row = wg / NCOLT; col = wg - row * NCOLT;
    }
    const int rowBase = row * 128;
    const int colBase = col * 128;

    // stage one 128x32 tile (8 KB): linear LDS dest, inverse-swizzled source
    auto stage = [&](const ushort* __restrict__ G, ushort* dst, int grow0, int kt) {
#pragma unroll
        for (int i = 0; i < 2; ++i) {
            const int l  = i * 256 + t;
            const int rl = l >> 2;                       // row (4 thr/row)
            const int sl = (l & 3) ^ (rl & 3);           // swizzled 16B slot
            load_lds16(G + (size_t)(grow0 + rl) * K + kt * BK + sl * 8,
                       dst + l * 8);
        }
    };

    floatx4 acc[4][4];
#pragma unroll
    for (int i = 0; i < 4; ++i)
#pragma unroll
        for (int j = 0; j < 4; ++j)
#pragma unroll
            for (int r2 = 0; r2 < 4; ++r2) acc[i][j][r2] = 0.f;

    // read-side swizzled slot offset (ushort units): logical slot fq
    const int s0 = (fq ^ f3) * 8;

    // prologue: tile 0 -> buffer 0
    stage(A, sA, rowBase, 0);
    stage(W, sB, colBase, 0);

    for (int kt = 0; kt < NTK; ++kt) {
        __syncthreads();                     // drains vm+lgkm: buf[cur] ready,
                                             // buf[cur^1] reads complete
        const int cb = (kt & 1) << 12;       // current buffer (ushort offset)
        if (kt + 1 < NTK) {                  // prefetch next tile
            stage(A, sA + (cb ^ 4096), rowBase, kt + 1);
            stage(W, sB + (cb ^ 4096), colBase, kt + 1);
        }

        const ushort* pa = sA + cb + (wm + fr) * BK;
        const ushort* pb = sB + cb + (wn + fr) * BK;
        short8 af[4], bf[4];
#pragma unroll
        for (int i = 0; i < 4; ++i) {
            af[i] = *(const short8*)(pa + i * 512 + s0);
            bf[i] = *(const short8*)(pb + i * 512 + s0);
        }
#pragma unroll
        for (int i = 0; i < 4; ++i)
#pragma unroll
            for (int j = 0; j < 4; ++j)
                acc[i][j] = __builtin_amdgcn_mfma_f32_16x16x32_bf16(
                    af[i], bf[j], acc[i][j], 0, 0, 0);
    }

    // epilogue: C/D layout col(n)=lane&15, row(m)=(lane>>4)*4+reg
    const int hpw = wm >> 6;                 // this wave's row-half
    if (MODE == 0) {
        // LDS-restaged fp32 stores: [64][128] float tile = 32 KiB exactly
        float (*Tf)[128] = (float (*)[128])smem;
#pragma unroll
        for (int hp = 0; hp < 2; ++hp) {
            __syncthreads();                 // prior smem uses complete
            if (hpw == hp) {
#pragma unroll
                for (int j = 0; j < 4; ++j) {
                    const int nl = wn + j * 16 + fr;
                    const float bq = bias[colBase + nl];
#pragma unroll
                    for (int i = 0; i < 4; ++i)
#pragma unroll
                        for (int r2 = 0; r2 < 4; ++r2)
                            Tf[i * 16 + fq * 4 + r2][nl] = acc[i][j][r2] + bq;
                }
            }
            __syncthreads();
            const int rowH = rowBase + hp * 64;
#pragma unroll
            for (int it = 0; it < 8; ++it) {
                const int lr = it * 8 + (t >> 5);       // 0..63
                const int c4 = (t & 31) * 4;            // float col
                const int mm = rowH + lr;
                if (mm < Mvalid)
                    *(float4*)(O0f + (size_t)mm * N + colBase + c4) =
                        *(const float4*)&Tf[lr][c4];
            }
        }
    } else {
        // LDS-restaged coalesced bf16 stores: two 64-row passes through smem
        const int which = colBase / CDIM;       // 0=q 1=k 2=v, block-uniform
        const int nc0   = colBase - which * CDIM;
        const int hbase = nc0 >> 6;
        ushort (*T)[136] = (ushort (*)[136])smem;   // 64 x 136 = 17 KiB
#pragma unroll
        for (int hp = 0; hp < 2; ++hp) {
            __syncthreads();                    // prior reads/writes of smem done
            if (hpw == hp) {
#pragma unroll
                for (int j = 0; j < 4; ++j) {
                    const int nl = wn + j * 16 + fr;
                    const float bq = bias[colBase + nl];
#pragma unroll
                    for (int i = 0; i < 4; ++i)
#pragma unroll
                        for (int r2 = 0; r2 < 4; ++r2)
                            T[i * 16 + fq * 4 + r2][nl] = f2bf(acc[i][j][r2] + bq);
                }
            }
            __syncthreads();
            const int rowH = rowBase + hp * 64;
            if (which < 2) {
                ushort* O = (which == 0) ? O0q : O1k;
#pragma unroll
                for (int it = 0; it < 4; ++it) {
                    const int run = it * 32 + (t >> 3);   // 64 rows x 2 heads
                    const int lr  = run >> 1;
                    const int hh  = run & 1;
                    const int d0  = (t & 7) * 8;
                    const int mm  = rowH + lr;
                    if (mm < Mvalid) {
                        const int b   = mm / NTOK;
                        const int tok = mm - b * NTOK;
                        *(short8*)(O + (((size_t)(b * NH + hbase + hh) * NTOK + tok) * HD + d0)) =
                            *(const short8*)&T[lr][hh * 64 + d0];
                    }
                }
            } else {
#pragma unroll
                for (int it = 0; it < 4; ++it) {
                    const int lr = it * 16 + (t >> 4);
                    const int c8 = (t & 15) * 8;
                    const int mm = rowH + lr;
                    if (mm < Mvalid)
                        *(short8*)(O2vd + ((size_t)mm * CDIM + nc0 + c8)) =
                            *(const short8*)&T[lr][c8];
                }
            }
        }
    }
}

// ---------------------------------------------------------------------------
// MFMA flash attention, one block per (b,h): 4 waves share an LDS-transposed
// V tile staged from the GEMM's dense v output via short8 loads.  Wave wv
// owns q-tile groups {0-3},{4-6},{7-9},{10-12}.  Tail blocks (>= BH) run the
// index-broadcast fill (grid-stride; overlaps the latency-bound attention).
// ---------------------------------------------------------------------------
constexpr int FILLB    = 256;                       // fill tail blocks
constexpr int FILL_TOT = BATCH * LEFT * (CDIM / 4); // float4s

__global__ __launch_bounds__(256) void attn_mfma_kernel(const ushort* __restrict__ Qb,
                                                        const ushort* __restrict__ Kb,
                                                        const ushort* __restrict__ Vd,
                                                        ushort* __restrict__ AOb,
                                                        const int* __restrict__ idxI,
                                                        float* __restrict__ fillDst) {
    if (blockIdx.x >= BH) {                 // block-uniform; no barriers touched
        const int fb = blockIdx.x - BH;
        for (int i = fb * 256 + (int)threadIdx.x; i < FILL_TOT; i += FILLB * 256) {
            const float v = (float)idxI[i / (CDIM / 4)];
            ((float4*)fillDst)[i] = make_float4(v, v, v, v);
        }
        return;
    }

    const int bh = blockIdx.x;          // 0..767
    const int b  = bh / NH;
    const int h  = bh - b * NH;
    const int t  = threadIdx.x;
    const int wv   = t >> 6;
    const int lane = t & 63;
    const int qc   = lane & 15;
    const int quad = lane >> 4;

    constexpr int VSTR = KPAD + 8;      // 232 ushorts (464B rows, 16B-aligned)
    __shared__ ushort Vt[HD][VSTR];     // 29.7 KiB
    __shared__ ushort Pl[4][4][16][32]; // 16 KiB (per wave x per tile)
    __shared__ float  alf[4][4][16], lf[4][4][16];

    // stage V transposed: each thread loads 8 consecutive d's of one tok (16B)
    {
        for (int idx = t; idx < NTOK * 8; idx += 256) {
            const int tok = idx >> 3;
            const int d0  = (idx & 7) * 8;
            const short8 v = *(const short8*)(
                Vd + ((size_t)(b * NTOK + tok)) * CDIM + h * HD + d0);
#pragma unroll
            for (int jj = 0; jj < 8; ++jj) Vt[d0 + jj][tok] = (ushort)v[jj];
        }
        for (int idx = t; idx < (KPAD - NTOK) * HD; idx += 256) {
            const int tok = NTOK + (idx >> 6);
            const int d   = idx & 63;
            Vt[d][tok] = 0;
        }
    }

    const ushort* Qh = Qb + (size_t)bh * NTOK * HD;
    const ushort* Kh = Kb + (size_t)bh * NTOK * HD;

    const int tile0 = (wv == 0) ? 0 : 4 + (wv - 1) * 3;   // 0,4,7,10
    const int ntv   = (wv == 0) ? 4 : 3;

    short8 qf[4][2];
#pragma unroll
    for (int ti = 0; ti < 4; ++ti) {
        if (ti < ntv) {
            const int qrow = min((tile0 + ti) * 16 + qc, NTOK - 1);
            qf[ti][0] = *(const short8*)(Qh + (size_t)qrow * HD + quad * 8);
            qf[ti][1] = *(const short8*)(Qh + (size_t)qrow * HD + 32 + quad * 8);
        }
    }

    floatx4 o[4][4];
#pragma unroll
    for (int ti = 0; ti < 4; ++ti)
#pragma unroll
        for (int s = 0; s < 4; ++s)
#pragma unroll
            for (int r = 0; r < 4; ++r) o[ti][s][r] = 0.f;
    float m[4], l[4];
#pragma unroll
    for (int ti = 0; ti < 4; ++ti) { m[ti] = -INFINITY; l[ti] = 0.f; }

    __syncthreads();                    // Vt ready

    for (int c0 = 0; c0 < NTOK; c0 += 32) {
        const int kr0 = min(c0 + qc, NTOK - 1);
        const int kr1 = min(c0 + 16 + qc, NTOK - 1);
        const short8 kf00 = *(const short8*)(Kh + (size_t)kr0 * HD + quad * 8);
        const short8 kf01 = *(const short8*)(Kh + (size_t)kr0 * HD + 32 + quad * 8);
        const short8 kf10 = *(const short8*)(Kh + (size_t)kr1 * HD + quad * 8);
        const short8 kf11 = *(const short8*)(Kh + (size_t)kr1 * HD + 32 + quad * 8);

#pragma unroll
        for (int ti = 0; ti < 4; ++ti) {
            if (ti >= ntv) continue;    // wave-uniform guard
            floatx4 s0 = {0.f, 0.f, 0.f, 0.f}, s1 = {0.f, 0.f, 0.f, 0.f};
            s0 = __builtin_amdgcn_mfma_f32_16x16x32_bf16(kf00, qf[ti][0], s0, 0, 0, 0);
            s0 = __builtin_amdgcn_mfma_f32_16x16x32_bf16(kf01, qf[ti][1], s0, 0, 0, 0);
            s1 = __builtin_amdgcn_mfma_f32_16x16x32_bf16(kf10, qf[ti][0], s1, 0, 0, 0);
            s1 = __builtin_amdgcn_mfma_f32_16x16x32_bf16(kf11, qf[ti][1], s1, 0, 0, 0);

            float sv[8];
            float mloc = -INFINITY;
#pragma unroll
            for (int r = 0; r < 4; ++r) {
                const int key0 = c0 + quad * 4 + r;
                const int key1 = key0 + 16;
                sv[r]     = (key0 < NTOK) ? s0[r] * 0.125f : -1e30f;
                sv[4 + r] = (key1 < NTOK) ? s1[r] * 0.125f : -1e30f;
                mloc = fmaxf(mloc, fmaxf(sv[r], sv[4 + r]));
            }
            mloc = fmaxf(mloc, __shfl_xor(mloc, 16));
            mloc = fmaxf(mloc, __shfl_xor(mloc, 32));
            const float mnew  = fmaxf(m[ti], mloc);
            const float alpha = __expf(m[ti] - mnew);
            float p[8], ps = 0.f;
#pragma unroll
            for (int i = 0; i < 8; ++i) { p[i] = __expf(sv[i] - mnew); ps += p[i]; }
            ps += __shfl_xor(ps, 16);
            ps += __shfl_xor(ps, 32);
            l[ti] = l[ti] * alpha + ps;
            m[ti] = mnew;

#pragma unroll
            for (int r = 0; r < 4; ++r) {
                Pl[wv][ti][qc][quad * 4 + r]      = f2bf(p[r]);
                Pl[wv][ti][qc][16 + quad * 4 + r] = f2bf(p[4 + r]);
            }
            if (quad == 0) alf[wv][ti][qc] = alpha;
        }
        __syncthreads();

        short8 pf[4];
#pragma unroll
        for (int ti = 0; ti < 4; ++ti) {
            if (ti >= ntv) continue;
            pf[ti] = *(const short8*)&Pl[wv][ti][qc][quad * 8];
            float ar[4];
#pragma unroll
            for (int r = 0; r < 4; ++r) ar[r] = alf[wv][ti][quad * 4 + r];
#pragma unroll
            for (int s = 0; s < 4; ++s)
#pragma unroll
                for (int r = 0; r < 4; ++r) o[ti][s][r] *= ar[r];
        }

#pragma unroll
        for (int s = 0; s < 4; ++s) {
            const short8 vf = *(const short8*)&Vt[s * 16 + qc][c0 + quad * 8];
#pragma unroll
            for (int ti = 0; ti < 4; ++ti)
                if (ti < ntv)
                    o[ti][s] = __builtin_amdgcn_mfma_f32_16x16x32_bf16(
                        pf[ti], vf, o[ti][s], 0, 0, 0);
        }
        __syncthreads();                // Pl reused next step
    }

#pragma unroll
    for (int ti = 0; ti < 4; ++ti)
        if (ti < ntv && quad == 0) lf[wv][ti][qc] = l[ti];
    __syncthreads();

#pragma unroll
    for (int ti = 0; ti < 4; ++ti) {
        if (ti >= ntv) continue;
        const int qt = tile0 + ti;
#pragma unroll
        for (int r = 0; r < 4; ++r) {
            const int tok = qt * 16 + quad * 4 + r;
            if (tok >= NTOK) continue;
            const float inv = 1.f / lf[wv][ti][quad * 4 + r];
            ushort* dst = AOb + ((size_t)(b * NTOK + tok)) * CDIM + h * HD;
#pragma unroll
            for (int s = 0; s < 4; ++s) dst[s * 16 + qc] = f2bf(o[ti][s][r] * inv);
        }
    }
}

// ---------------------------------------------------------------------------
// Fused cls softmax (per head, exact fp32) + head-average + exact top-137
// (stable descending) + cls output. One block per batch.
// ---------------------------------------------------------------------------
__global__ __launch_bounds__(256) void topk_fused_kernel(const float* __restrict__ S,
                                                         const float* __restrict__ qbW,
                                                         int* __restrict__ idxI,
                                                         float* __restrict__ idxOut,
                                                         float* __restrict__ outCls) {
    const int b    = blockIdx.x;
    const int t    = threadIdx.x;
    const int lane = t & 63;
    const int w    = t >> 6;

    __shared__ float qbv[NH];
    __shared__ float redm[4], reds[4];
    __shared__ float vsh[NTOK - 1];

    if (t < NH) qbv[t] = qbW[b * NH + t];
    __syncthreads();

    float macc = 0.f;
    for (int h = 0; h < NH; ++h) {
        const float qb = qbv[h];
        const float sv = (t < NTOK) ? (S[(size_t)(b * NH + h) * SPAD + t] + qb) * 0.125f
                                    : -INFINITY;
        float mloc = sv;
#pragma unroll
        for (int off = 32; off >= 1; off >>= 1) mloc = fmaxf(mloc, __shfl_xor(mloc, off));
        if (lane == 0) redm[w] = mloc;
        __syncthreads();
        const float mx = fmaxf(fmaxf(redm[0], redm[1]), fmaxf(redm[2], redm[3]));
        const float p = (t < NTOK) ? expf(sv - mx) : 0.f;
        float ls = p;
#pragma unroll
        for (int off = 32; off >= 1; off >>= 1) ls += __shfl_xor(ls, off);
        if (lane == 0) reds[w] = ls;
        __syncthreads();
        const float denom = (reds[0] + reds[1]) + (reds[2] + reds[3]);
        macc += p / denom;
        __syncthreads();                  // protect redm/reds for next h
    }

    if (t >= 1 && t < NTOK) {
        const float val = macc * (1.f / 12.f);
        vsh[t - 1] = val;
        outCls[(size_t)b * (NTOK - 1) + (t - 1)] = val;
    }
    __syncthreads();

    if (t < NTOK - 1) {
        const float vi = vsh[t];
        int rank = 0;
        for (int j = 0; j < NTOK - 1; j++) {
            const float vj = vsh[j];
            rank += (vj > vi) || (vj == vi && j < t);
        }
        if (rank < LEFT) {
            idxI[b * LEFT + rank]   = t;
            idxOut[b * LEFT + rank] = (float)t;
        }
    }
}

extern "C" void kernel_launch(void* const* d_in, const int* in_sizes, int n_in,
                              void* d_out, int out_size, void* d_ws, size_t ws_size,
                              hipStream_t stream) {
    const float* x      = (const float*)d_in[0];
    const float* qkv_w  = (const float*)d_in[1];  // [2304,768]
    const float* qkv_b  = (const float*)d_in[2];  // [2304]
    const float* proj_w = (const float*)d_in[3];  // [768,768]
    const float* proj_b = (const float*)d_in[4];  // [768]
    float* out = (float*)d_out;

    float*  ws    = (float*)d_ws;
    int*    idxi  = (int*)(ws + WS_IDXI);
    float*  qbW   = ws + WS_Q0;
    ushort* xb    = (ushort*)(ws + WS_XB);
    ushort* wb    = (ushort*)(ws + WS_WB);
    ushort* pb    = (ushort*)(ws + WS_PB);
    ushort* qb    = (ushort*)(ws + WS_QB);
    ushort* kb    = (ushort*)(ws + WS_KB);
    ushort* vd    = (ushort*)(ws + WS_VTB);  // dense v [MROWS][768]
    ushort* aob   = (ushort*)(ws + WS_AOB);
    float*  U     = ws + WS_U;
    float*  S     = ws + WS_S;

    // 1) fused prep: bf16 casts + exact fp32 q0/qb/U side path
    prep_kernel<<<CASTB + BH, 256, 0, stream>>>(x, qkv_w, proj_w, qkv_b,
                                                xb, wb, pb, U, qbW);

    // 2) cls scores (LDS-staged U, 8 j's/block, 1600-block parallelism)
    score_kernel<<<dim3((NTOK + 7) / 8, BATCH), 512, 0, stream>>>(x, U, S);

    // 3) cls softmax + head-average + exact top-137 (side path complete)
    topk_fused_kernel<<<BATCH, 256, 0, stream>>>(S, qbW, idxi,
                                                 out + OUT_OFF_IDX,
                                                 out + OUT_OFF_CLS);

    // 4) QKV projection (128²/BK32 MFMA) + LDS-restaged coalesced q/k/v stores
    mfma_gemm128<1, 18><<<NROWT * 18, 256, 0, stream>>>(
        xb, wb, qkv_b, nullptr, qb, kb, vd, MROWS, 3 * CDIM);

    // 5) MFMA flash attention (block per bh; in-LDS V transpose) -> bf16 out;
    //    fill_index piggybacked on 256 tail blocks (overlaps attn latency)
    attn_mfma_kernel<<<BH + FILLB, 256, 0, stream>>>(qb, kb, vd, aob,
                                                     idxi, out + OUT_OFF_INDEX);

    // 6) Output projection (128²/BK32 MFMA, LDS-restaged fp32 stores)
    mfma_gemm128<0, 6><<<NROWT * 6, 256, 0, stream>>>(
        aob, pb, proj_b, out + OUT_OFF_OUT, nullptr, nullptr, nullptr,
        MROWS, CDIM);
}